// Round 3
// baseline (173.804 us; speedup 1.0000x reference)
//
#include <hip/hip_runtime.h>

#define N_ATOMS 5000
#define N_EDGES 40000
#define N_TRIP  250000
#define NH      4
#define NHID    64
#define NOUT    64
#define NTYPES  108
#define NPAIRS  (NTYPES * NTYPES)
#define EPSV    0.001f
#define PI_F    3.14159265358979323846f

// ---------------------------------------------------------------------------
// K1: per-edge atomic types + 108x108 per-head key dot-product table
// ---------------------------------------------------------------------------
__global__ void prep_kernel(const float* __restrict__ key_emb,
                            const int* __restrict__ src_idx,
                            const int* __restrict__ dst_idx,
                            const int* __restrict__ atomic_number,
                            float* __restrict__ W,
                            int* __restrict__ za_e,
                            int* __restrict__ zb_e) {
    int tid = blockIdx.x * blockDim.x + threadIdx.x;
    if (tid < N_EDGES) {
        za_e[tid] = atomic_number[src_idx[tid]];
        zb_e[tid] = atomic_number[dst_idx[tid]];
    }
    if (tid < NPAIRS) {
        int za = tid / NTYPES;
        int zb = tid - za * NTYPES;
        const float* ra = key_emb + za * (NHID * NH);
        const float* rb = key_emb + zb * (NHID * NH);
        float acc0 = 0.f, acc1 = 0.f, acc2 = 0.f, acc3 = 0.f;
        #pragma unroll 8
        for (int i = 0; i < NHID; ++i) {
            float4 va = *reinterpret_cast<const float4*>(ra + i * NH);
            float4 vb = *reinterpret_cast<const float4*>(rb + i * NH);
            acc0 += va.x * vb.x;
            acc1 += va.y * vb.y;
            acc2 += va.z * vb.z;
            acc3 += va.w * vb.w;
        }
        float* wp = W + tid * NH;
        wp[0] = acc0; wp[1] = acc1; wp[2] = acc2; wp[3] = acc3;
    }
}

// ---------------------------------------------------------------------------
// K2: histograms of lg_src (triplet->edge) and src_idx (edge->atom)
// ---------------------------------------------------------------------------
__global__ void hist_kernel(const int* __restrict__ lg_src,
                            const int* __restrict__ src_idx,
                            int* __restrict__ histT,
                            int* __restrict__ histE) {
    int tid = blockIdx.x * blockDim.x + threadIdx.x;
    if (tid < N_TRIP)  atomicAdd(&histT[lg_src[tid]], 1);
    if (tid < N_EDGES) atomicAdd(&histE[src_idx[tid]], 1);
}

// ---------------------------------------------------------------------------
// K3: exclusive scans (one block). start = exclusive prefix; next = copy.
// ---------------------------------------------------------------------------
__device__ void scan_block(const int* __restrict__ hist, int n,
                           int* __restrict__ start, int* __restrict__ next,
                           int* lds) {
    int tid = threadIdx.x;
    int per = (n + 255) / 256;
    int lo = tid * per;
    int hi = lo + per; if (hi > n) hi = n;
    int s = 0;
    for (int i = lo; i < hi; ++i) s += hist[i];
    lds[tid] = s;
    __syncthreads();
    for (int off = 1; off < 256; off <<= 1) {
        int v = (tid >= off) ? lds[tid - off] : 0;
        __syncthreads();
        lds[tid] += v;
        __syncthreads();
    }
    int carry = (tid == 0) ? 0 : lds[tid - 1];
    for (int i = lo; i < hi; ++i) {
        start[i] = carry;
        next[i]  = carry;
        carry += hist[i];
    }
    __syncthreads();
}

__global__ void scan_kernel(const int* __restrict__ histT, const int* __restrict__ histE,
                            int* __restrict__ startT, int* __restrict__ nextT,
                            int* __restrict__ startE, int* __restrict__ nextE) {
    __shared__ int lds[256];
    scan_block(histT, N_EDGES, startT, nextT, lds);
    scan_block(histE, N_ATOMS, startE, nextE, lds);
}

// ---------------------------------------------------------------------------
// K4: per-triplet geometry + per-head value; non-atomic write to sorted slot
// ---------------------------------------------------------------------------
__global__ void trip_kernel(const float* __restrict__ r,
                            const float* __restrict__ dnr,
                            const float* __restrict__ a_p,
                            const float* __restrict__ b_p,
                            const float* __restrict__ c_p,
                            const float* __restrict__ d_p,
                            const int* __restrict__ lg_src,
                            const int* __restrict__ lg_dst,
                            const int* __restrict__ za_e,
                            const int* __restrict__ zb_e,
                            const float* __restrict__ W,
                            int* __restrict__ nextT,
                            float4* __restrict__ val_sorted) {
    int t = blockIdx.x * blockDim.x + threadIdx.x;
    if (t >= N_TRIP) return;

    int e1 = lg_src[t];
    int e2 = lg_dst[t];

    float ax = r[e1 * 3 + 0];
    float ay = r[e1 * 3 + 1];
    float az = r[e1 * 3 + 2];
    float bx = r[e2 * 3 + 0];
    float by = r[e2 * 3 + 1];
    float bz = r[e2 * 3 + 2];

    // r1 = -r[e1], r2 = r[e2]  -> dot = -(a.b)
    float dot = -(ax * bx + ay * by + az * bz);
    float n1  = sqrtf(ax * ax + ay * ay + az * az);
    float n2  = sqrtf(bx * bx + by * by + bz * bz);
    float cosv = dot / (n1 * n2);
    cosv = fminf(fmaxf(cosv, -1.0f), 1.0f);
    cosv = fminf(fmaxf(cosv, -EPSV), EPSV);
    float theta = acosf(cosv);

    float dn  = dnr[t];
    float dn2 = dn * dn;

    const float* wp = W + (za_e[e1] * NTYPES + zb_e[e2]) * NH;

    float v[NH];
    #pragma unroll
    for (int h = 0; h < NH; ++h) {
        float A = a_p[h];
        float B = fmodf(b_p[h], PI_F);
        float C = c_p[h];
        float D = d_p[h];
        float ang = powf((cosf(A * theta + B) + 1.0f) * 0.5f, C);
        float rad = expf(-D * dn2);
        v[h] = wp[h] * ang * rad;
    }

    int pos = atomicAdd(&nextT[e1], 1);
    val_sorted[pos] = make_float4(v[0], v[1], v[2], v[3]);
}

// ---------------------------------------------------------------------------
// K5: per-edge segmented mean over its triplets + edge->atom slot scatter
// ---------------------------------------------------------------------------
__global__ void edge_kernel(const int* __restrict__ src_idx,
                            const int* __restrict__ histT,
                            const int* __restrict__ startT,
                            const float4* __restrict__ val_sorted,
                            int* __restrict__ nextE,
                            int* __restrict__ edge_ord,
                            float4* __restrict__ edge_val) {
    int e = blockIdx.x * blockDim.x + threadIdx.x;
    if (e >= N_EDGES) return;

    int cnt = histT[e];
    int st  = startT[e];
    float sx = 0.f, sy = 0.f, sz = 0.f, sw = 0.f;
    for (int p = st; p < st + cnt; ++p) {
        float4 v = val_sorted[p];
        sx += v.x; sy += v.y; sz += v.z; sw += v.w;
    }
    float inv = 1.0f / (float)(cnt > 1 ? cnt : 1);
    edge_val[e] = make_float4(sx * inv, sy * inv, sz * inv, sw * inv);

    int pos = atomicAdd(&nextE[src_idx[e]], 1);
    edge_ord[pos] = e;
}

// ---------------------------------------------------------------------------
// K6: per (atom, out): gather CSR edges, dot with value_emb, mean, store
// ---------------------------------------------------------------------------
__global__ void atom_kernel(const float* __restrict__ value_emb,
                            const int* __restrict__ zb_e,
                            const int* __restrict__ histE,
                            const int* __restrict__ startE,
                            const int* __restrict__ edge_ord,
                            const float4* __restrict__ edge_val,
                            float* __restrict__ out) {
    int id = blockIdx.x * blockDim.x + threadIdx.x;
    if (id >= N_ATOMS * NOUT) return;
    int n = id >> 6;
    int o = id & 63;

    int cnt = histE[n];
    int st  = startE[n];
    float acc = 0.f;
    for (int q = st; q < st + cnt; ++q) {
        int e = edge_ord[q];
        float4 m = edge_val[e];
        int zb = zb_e[e];
        float4 v = *reinterpret_cast<const float4*>(value_emb + zb * (NOUT * NH) + o * NH);
        acc += v.x * m.x + v.y * m.y + v.z * m.z + v.w * m.w;
    }
    out[id] = acc / (float)(cnt > 1 ? cnt : 1);
}

extern "C" void kernel_launch(void* const* d_in, const int* in_sizes, int n_in,
                              void* d_out, int out_size, void* d_ws, size_t ws_size,
                              hipStream_t stream) {
    const float* r         = (const float*)d_in[0];
    const float* dnr       = (const float*)d_in[1];
    const float* key_emb   = (const float*)d_in[2];
    const float* value_emb = (const float*)d_in[3];
    const float* a_p       = (const float*)d_in[4];
    const float* b_p       = (const float*)d_in[5];
    const float* c_p       = (const float*)d_in[6];
    const float* d_p       = (const float*)d_in[7];
    const int* src_idx   = (const int*)d_in[8];
    const int* dst_idx   = (const int*)d_in[9];
    const int* lg_src    = (const int*)d_in[10];
    const int* lg_dst    = (const int*)d_in[11];
    const int* atomic_number = (const int*)d_in[12];
    float* out = (float*)d_out;

    char* ws = (char*)d_ws;
    size_t off = 0;
    auto take = [&](size_t bytes) -> char* {
        char* p = ws + off;
        off = (off + bytes + 255) & ~(size_t)255;
        return p;
    };
    // zeroed region (histograms only)
    char*  zero_beg   = ws;
    int*   histT      = (int*)  take(N_EDGES * sizeof(int));
    int*   histE      = (int*)  take(N_ATOMS * sizeof(int));
    size_t zero_len   = (size_t)((ws + off) - zero_beg);
    // non-zeroed scratch
    int*    startT     = (int*)   take(N_EDGES * sizeof(int));
    int*    nextT      = (int*)   take(N_EDGES * sizeof(int));
    int*    startE     = (int*)   take(N_ATOMS * sizeof(int));
    int*    nextE      = (int*)   take(N_ATOMS * sizeof(int));
    int*    za_e       = (int*)   take(N_EDGES * sizeof(int));
    int*    zb_e       = (int*)   take(N_EDGES * sizeof(int));
    float*  W          = (float*) take(NPAIRS * NH * sizeof(float));
    int*    edge_ord   = (int*)   take(N_EDGES * sizeof(int));
    float4* edge_val   = (float4*)take(N_EDGES * sizeof(float4));
    float4* val_sorted = (float4*)take((size_t)N_TRIP * sizeof(float4));

    hipMemsetAsync(zero_beg, 0, zero_len, stream);

    {   // K1 prep: covers both N_EDGES and NPAIRS
        int n = (N_EDGES > NPAIRS ? N_EDGES : NPAIRS);
        prep_kernel<<<(n + 255) / 256, 256, 0, stream>>>(
            key_emb, src_idx, dst_idx, atomic_number, W, za_e, zb_e);
    }
    hist_kernel<<<(N_TRIP + 255) / 256, 256, 0, stream>>>(
        lg_src, src_idx, histT, histE);
    scan_kernel<<<1, 256, 0, stream>>>(
        histT, histE, startT, nextT, startE, nextE);
    trip_kernel<<<(N_TRIP + 255) / 256, 256, 0, stream>>>(
        r, dnr, a_p, b_p, c_p, d_p, lg_src, lg_dst, za_e, zb_e, W, nextT, val_sorted);
    edge_kernel<<<(N_EDGES + 255) / 256, 256, 0, stream>>>(
        src_idx, histT, startT, val_sorted, nextE, edge_ord, edge_val);
    atom_kernel<<<(N_ATOMS * NOUT + 255) / 256, 256, 0, stream>>>(
        value_emb, zb_e, histE, startE, edge_ord, edge_val, out);
}

// Round 4
// 76.655 us; speedup vs baseline: 2.2673x; 2.2673x over previous
//
#include <hip/hip_runtime.h>

#define N_ATOMS 5000
#define N_EDGES 40000
#define N_TRIP  250000
#define NH      4
#define NHID    64
#define NOUT    64
#define NTYPES  108
#define NPAIRS  (NTYPES * NTYPES)
#define EPSV    0.001f
#define PI_F    3.14159265358979323846f

#define SCAN_BT ((N_EDGES + 255) / 256)   // 157 blocks for triplet->edge hist
#define SCAN_BE ((N_ATOMS + 255) / 256)   // 20 blocks for edge->atom hist
#define SCAN_NB (SCAN_BT + SCAN_BE)       // 177

// ---------------------------------------------------------------------------
// K1: per-edge atomic types + 108x108 per-head key dot-product table
// ---------------------------------------------------------------------------
__global__ void prep_kernel(const float* __restrict__ key_emb,
                            const int* __restrict__ src_idx,
                            const int* __restrict__ dst_idx,
                            const int* __restrict__ atomic_number,
                            float* __restrict__ W,
                            int* __restrict__ za_e,
                            int* __restrict__ zb_e) {
    int tid = blockIdx.x * blockDim.x + threadIdx.x;
    if (tid < N_EDGES) {
        za_e[tid] = atomic_number[src_idx[tid]];
        zb_e[tid] = atomic_number[dst_idx[tid]];
    }
    if (tid < NPAIRS) {
        int za = tid / NTYPES;
        int zb = tid - za * NTYPES;
        const float* ra = key_emb + za * (NHID * NH);
        const float* rb = key_emb + zb * (NHID * NH);
        float acc0 = 0.f, acc1 = 0.f, acc2 = 0.f, acc3 = 0.f;
        #pragma unroll 8
        for (int i = 0; i < NHID; ++i) {
            float4 va = *reinterpret_cast<const float4*>(ra + i * NH);
            float4 vb = *reinterpret_cast<const float4*>(rb + i * NH);
            acc0 += va.x * vb.x;
            acc1 += va.y * vb.y;
            acc2 += va.z * vb.z;
            acc3 += va.w * vb.w;
        }
        float* wp = W + tid * NH;
        wp[0] = acc0; wp[1] = acc1; wp[2] = acc2; wp[3] = acc3;
    }
}

// ---------------------------------------------------------------------------
// K2: histograms + rank assignment (returning atomics, TLP-hidden)
// ---------------------------------------------------------------------------
__global__ void hist_kernel(const int* __restrict__ lg_src,
                            const int* __restrict__ src_idx,
                            int* __restrict__ histT,
                            int* __restrict__ histE,
                            int* __restrict__ rankT,
                            int* __restrict__ rankE) {
    int tid = blockIdx.x * blockDim.x + threadIdx.x;
    if (tid < N_TRIP)  rankT[tid] = atomicAdd(&histT[lg_src[tid]], 1);
    if (tid < N_EDGES) rankE[tid] = atomicAdd(&histE[src_idx[tid]], 1);
}

// ---------------------------------------------------------------------------
// K3a: per-block sums of both histograms
// ---------------------------------------------------------------------------
__global__ void scanA_kernel(const int* __restrict__ histT,
                             const int* __restrict__ histE,
                             int* __restrict__ blocksum) {
    __shared__ int lds[256];
    int b = blockIdx.x;
    int tid = threadIdx.x;
    int v = 0;
    if (b < SCAN_BT) {
        int i = b * 256 + tid;
        if (i < N_EDGES) v = histT[i];
    } else {
        int i = (b - SCAN_BT) * 256 + tid;
        if (i < N_ATOMS) v = histE[i];
    }
    lds[tid] = v;
    __syncthreads();
    for (int off = 128; off > 0; off >>= 1) {
        if (tid < off) lds[tid] += lds[tid + off];
        __syncthreads();
    }
    if (tid == 0) blocksum[b] = lds[0];
}

// ---------------------------------------------------------------------------
// K3b: exclusive scan of the block sums (two independent domains)
// ---------------------------------------------------------------------------
__device__ __forceinline__ void small_excl_scan(int* lds, int tid, int n,
                                                const int* __restrict__ in,
                                                int* __restrict__ outp, int in_off) {
    int v = (tid < n) ? in[in_off + tid] : 0;
    lds[tid] = v;
    __syncthreads();
    for (int off = 1; off < 256; off <<= 1) {
        int u = (tid >= off) ? lds[tid - off] : 0;
        __syncthreads();
        lds[tid] += u;
        __syncthreads();
    }
    int excl = (tid == 0) ? 0 : lds[tid - 1];
    if (tid < n) outp[in_off + tid] = excl;
    __syncthreads();
}

__global__ void scanB_kernel(const int* __restrict__ blocksum,
                             int* __restrict__ blockoff) {
    __shared__ int lds[256];
    int tid = threadIdx.x;
    small_excl_scan(lds, tid, SCAN_BT, blocksum, blockoff, 0);
    small_excl_scan(lds, tid, SCAN_BE, blocksum, blockoff, SCAN_BT);
}

// ---------------------------------------------------------------------------
// K3c: block-local exclusive scan + block offset -> startT / startE
// ---------------------------------------------------------------------------
__global__ void scanC_kernel(const int* __restrict__ histT,
                             const int* __restrict__ histE,
                             const int* __restrict__ blockoff,
                             int* __restrict__ startT,
                             int* __restrict__ startE) {
    __shared__ int lds[256];
    int b = blockIdx.x;
    int tid = threadIdx.x;
    const int* hist;
    int* start;
    int n, base;
    if (b < SCAN_BT) { hist = histT; start = startT; n = N_EDGES; base = b * 256; }
    else             { hist = histE; start = startE; n = N_ATOMS; base = (b - SCAN_BT) * 256; }
    int i = base + tid;
    int v = (i < n) ? hist[i] : 0;
    lds[tid] = v;
    __syncthreads();
    for (int off = 1; off < 256; off <<= 1) {
        int u = (tid >= off) ? lds[tid - off] : 0;
        __syncthreads();
        lds[tid] += u;
        __syncthreads();
    }
    int excl = ((tid == 0) ? 0 : lds[tid - 1]) + blockoff[b];
    if (i < n) start[i] = excl;
}

// ---------------------------------------------------------------------------
// K4: per-triplet geometry + per-head value; non-atomic write to sorted slot
// ---------------------------------------------------------------------------
__global__ void trip_kernel(const float* __restrict__ r,
                            const float* __restrict__ dnr,
                            const float* __restrict__ a_p,
                            const float* __restrict__ b_p,
                            const float* __restrict__ c_p,
                            const float* __restrict__ d_p,
                            const int* __restrict__ lg_src,
                            const int* __restrict__ lg_dst,
                            const int* __restrict__ za_e,
                            const int* __restrict__ zb_e,
                            const float* __restrict__ W,
                            const int* __restrict__ startT,
                            const int* __restrict__ rankT,
                            float4* __restrict__ val_sorted) {
    int t = blockIdx.x * blockDim.x + threadIdx.x;
    if (t >= N_TRIP) return;

    int e1 = lg_src[t];
    int e2 = lg_dst[t];

    float ax = r[e1 * 3 + 0];
    float ay = r[e1 * 3 + 1];
    float az = r[e1 * 3 + 2];
    float bx = r[e2 * 3 + 0];
    float by = r[e2 * 3 + 1];
    float bz = r[e2 * 3 + 2];

    // r1 = -r[e1], r2 = r[e2]  -> dot = -(a.b)
    float dot = -(ax * bx + ay * by + az * bz);
    float n1  = sqrtf(ax * ax + ay * ay + az * az);
    float n2  = sqrtf(bx * bx + by * by + bz * bz);
    float cosv = dot / (n1 * n2);
    cosv = fminf(fmaxf(cosv, -1.0f), 1.0f);
    cosv = fminf(fmaxf(cosv, -EPSV), EPSV);
    float theta = acosf(cosv);

    float dn  = dnr[t];
    float dn2 = dn * dn;

    const float* wp = W + (za_e[e1] * NTYPES + zb_e[e2]) * NH;

    float v[NH];
    #pragma unroll
    for (int h = 0; h < NH; ++h) {
        float A = a_p[h];
        float B = fmodf(b_p[h], PI_F);
        float C = c_p[h];
        float D = d_p[h];
        float ang = powf((cosf(A * theta + B) + 1.0f) * 0.5f, C);
        float rad = expf(-D * dn2);
        v[h] = wp[h] * ang * rad;
    }

    val_sorted[startT[e1] + rankT[t]] = make_float4(v[0], v[1], v[2], v[3]);
}

// ---------------------------------------------------------------------------
// K5: per-edge segmented mean over its triplets + edge->atom slot scatter
// ---------------------------------------------------------------------------
__global__ void edge_kernel(const int* __restrict__ src_idx,
                            const int* __restrict__ histT,
                            const int* __restrict__ startT,
                            const int* __restrict__ startE,
                            const int* __restrict__ rankE,
                            const float4* __restrict__ val_sorted,
                            int* __restrict__ edge_ord,
                            float4* __restrict__ edge_val) {
    int e = blockIdx.x * blockDim.x + threadIdx.x;
    if (e >= N_EDGES) return;

    int cnt = histT[e];
    int st  = startT[e];
    float sx = 0.f, sy = 0.f, sz = 0.f, sw = 0.f;
    for (int p = st; p < st + cnt; ++p) {
        float4 v = val_sorted[p];
        sx += v.x; sy += v.y; sz += v.z; sw += v.w;
    }
    float inv = 1.0f / (float)(cnt > 1 ? cnt : 1);
    edge_val[e] = make_float4(sx * inv, sy * inv, sz * inv, sw * inv);

    edge_ord[startE[src_idx[e]] + rankE[e]] = e;
}

// ---------------------------------------------------------------------------
// K6: per (atom, out): gather CSR edges, dot with value_emb, mean, store
// ---------------------------------------------------------------------------
__global__ void atom_kernel(const float* __restrict__ value_emb,
                            const int* __restrict__ zb_e,
                            const int* __restrict__ histE,
                            const int* __restrict__ startE,
                            const int* __restrict__ edge_ord,
                            const float4* __restrict__ edge_val,
                            float* __restrict__ out) {
    int id = blockIdx.x * blockDim.x + threadIdx.x;
    if (id >= N_ATOMS * NOUT) return;
    int n = id >> 6;
    int o = id & 63;

    int cnt = histE[n];
    int st  = startE[n];
    float acc = 0.f;
    for (int q = st; q < st + cnt; ++q) {
        int e = edge_ord[q];
        float4 m = edge_val[e];
        int zb = zb_e[e];
        float4 v = *reinterpret_cast<const float4*>(value_emb + zb * (NOUT * NH) + o * NH);
        acc += v.x * m.x + v.y * m.y + v.z * m.z + v.w * m.w;
    }
    out[id] = acc / (float)(cnt > 1 ? cnt : 1);
}

extern "C" void kernel_launch(void* const* d_in, const int* in_sizes, int n_in,
                              void* d_out, int out_size, void* d_ws, size_t ws_size,
                              hipStream_t stream) {
    const float* r         = (const float*)d_in[0];
    const float* dnr       = (const float*)d_in[1];
    const float* key_emb   = (const float*)d_in[2];
    const float* value_emb = (const float*)d_in[3];
    const float* a_p       = (const float*)d_in[4];
    const float* b_p       = (const float*)d_in[5];
    const float* c_p       = (const float*)d_in[6];
    const float* d_p       = (const float*)d_in[7];
    const int* src_idx   = (const int*)d_in[8];
    const int* dst_idx   = (const int*)d_in[9];
    const int* lg_src    = (const int*)d_in[10];
    const int* lg_dst    = (const int*)d_in[11];
    const int* atomic_number = (const int*)d_in[12];
    float* out = (float*)d_out;

    char* ws = (char*)d_ws;
    size_t off = 0;
    auto take = [&](size_t bytes) -> char* {
        char* p = ws + off;
        off = (off + bytes + 255) & ~(size_t)255;
        return p;
    };
    // zeroed region (histograms only — must lead the workspace)
    char*  zero_beg   = ws;
    int*   histT      = (int*)  take(N_EDGES * sizeof(int));
    int*   histE      = (int*)  take(N_ATOMS * sizeof(int));
    size_t zero_len   = (size_t)((ws + off) - zero_beg);
    // non-zeroed scratch
    int*    rankT      = (int*)   take((size_t)N_TRIP * sizeof(int));
    int*    rankE      = (int*)   take(N_EDGES * sizeof(int));
    int*    startT     = (int*)   take(N_EDGES * sizeof(int));
    int*    startE     = (int*)   take(N_ATOMS * sizeof(int));
    int*    blocksum   = (int*)   take(SCAN_NB * sizeof(int));
    int*    blockoff   = (int*)   take(SCAN_NB * sizeof(int));
    int*    za_e       = (int*)   take(N_EDGES * sizeof(int));
    int*    zb_e       = (int*)   take(N_EDGES * sizeof(int));
    float*  W          = (float*) take(NPAIRS * NH * sizeof(float));
    int*    edge_ord   = (int*)   take(N_EDGES * sizeof(int));
    float4* edge_val   = (float4*)take(N_EDGES * sizeof(float4));
    float4* val_sorted = (float4*)take((size_t)N_TRIP * sizeof(float4));

    hipMemsetAsync(zero_beg, 0, zero_len, stream);

    {   // K1 prep: covers both N_EDGES and NPAIRS
        int n = (N_EDGES > NPAIRS ? N_EDGES : NPAIRS);
        prep_kernel<<<(n + 255) / 256, 256, 0, stream>>>(
            key_emb, src_idx, dst_idx, atomic_number, W, za_e, zb_e);
    }
    hist_kernel<<<(N_TRIP + 255) / 256, 256, 0, stream>>>(
        lg_src, src_idx, histT, histE, rankT, rankE);
    scanA_kernel<<<SCAN_NB, 256, 0, stream>>>(histT, histE, blocksum);
    scanB_kernel<<<1, 256, 0, stream>>>(blocksum, blockoff);
    scanC_kernel<<<SCAN_NB, 256, 0, stream>>>(histT, histE, blockoff, startT, startE);
    trip_kernel<<<(N_TRIP + 255) / 256, 256, 0, stream>>>(
        r, dnr, a_p, b_p, c_p, d_p, lg_src, lg_dst, za_e, zb_e, W,
        startT, rankT, val_sorted);
    edge_kernel<<<(N_EDGES + 255) / 256, 256, 0, stream>>>(
        src_idx, histT, startT, startE, rankE, val_sorted, edge_ord, edge_val);
    atom_kernel<<<(N_ATOMS * NOUT + 255) / 256, 256, 0, stream>>>(
        value_emb, zb_e, histE, startE, edge_ord, edge_val, out);
}

// Round 5
// 71.619 us; speedup vs baseline: 2.4268x; 1.0703x over previous
//
#include <hip/hip_runtime.h>

#define N_ATOMS 5000
#define N_EDGES 40000
#define N_TRIP  250000
#define NH      4
#define NHID    64
#define NOUT    64
#define NTYPES  108
#define NPAIRS  (NTYPES * NTYPES)
#define EPSV    0.001f
#define PI_F    3.14159265358979323846f

#define SCAN_BT ((N_EDGES + 255) / 256)   // 157 blocks for triplet->edge hist
#define SCAN_BE ((N_ATOMS + 255) / 256)   // 20 blocks for edge->atom hist
#define SCAN_NB (SCAN_BT + SCAN_BE)       // 177

// ---------------------------------------------------------------------------
// K1: zero histograms + per-edge atomic types + 108x108 key dot-product table
// (zeroing folded in here: grid covers max(N_EDGES,NPAIRS) >= all ranges,
//  stream order guarantees zeros land before hist_kernel)
// ---------------------------------------------------------------------------
__global__ void prep_kernel(const float* __restrict__ key_emb,
                            const int* __restrict__ src_idx,
                            const int* __restrict__ dst_idx,
                            const int* __restrict__ atomic_number,
                            float* __restrict__ W,
                            int* __restrict__ za_e,
                            int* __restrict__ zb_e,
                            int* __restrict__ histT,
                            int* __restrict__ histE) {
    int tid = blockIdx.x * blockDim.x + threadIdx.x;
    if (tid < N_EDGES) {
        za_e[tid] = atomic_number[src_idx[tid]];
        zb_e[tid] = atomic_number[dst_idx[tid]];
        histT[tid] = 0;
    }
    if (tid < N_ATOMS) histE[tid] = 0;
    if (tid < NPAIRS) {
        int za = tid / NTYPES;
        int zb = tid - za * NTYPES;
        const float* ra = key_emb + za * (NHID * NH);
        const float* rb = key_emb + zb * (NHID * NH);
        float acc0 = 0.f, acc1 = 0.f, acc2 = 0.f, acc3 = 0.f;
        #pragma unroll 8
        for (int i = 0; i < NHID; ++i) {
            float4 va = *reinterpret_cast<const float4*>(ra + i * NH);
            float4 vb = *reinterpret_cast<const float4*>(rb + i * NH);
            acc0 += va.x * vb.x;
            acc1 += va.y * vb.y;
            acc2 += va.z * vb.z;
            acc3 += va.w * vb.w;
        }
        float* wp = W + tid * NH;
        wp[0] = acc0; wp[1] = acc1; wp[2] = acc2; wp[3] = acc3;
    }
}

// ---------------------------------------------------------------------------
// K2: histograms + rank assignment (returning atomics, TLP-hidden)
// ---------------------------------------------------------------------------
__global__ void hist_kernel(const int* __restrict__ lg_src,
                            const int* __restrict__ src_idx,
                            int* __restrict__ histT,
                            int* __restrict__ histE,
                            int* __restrict__ rankT,
                            int* __restrict__ rankE) {
    int tid = blockIdx.x * blockDim.x + threadIdx.x;
    if (tid < N_TRIP)  rankT[tid] = atomicAdd(&histT[lg_src[tid]], 1);
    if (tid < N_EDGES) rankE[tid] = atomicAdd(&histE[src_idx[tid]], 1);
}

// ---------------------------------------------------------------------------
// K3a: per-block sums of both histograms
// ---------------------------------------------------------------------------
__global__ void scanA_kernel(const int* __restrict__ histT,
                             const int* __restrict__ histE,
                             int* __restrict__ blocksum) {
    __shared__ int lds[256];
    int b = blockIdx.x;
    int tid = threadIdx.x;
    int v = 0;
    if (b < SCAN_BT) {
        int i = b * 256 + tid;
        if (i < N_EDGES) v = histT[i];
    } else {
        int i = (b - SCAN_BT) * 256 + tid;
        if (i < N_ATOMS) v = histE[i];
    }
    lds[tid] = v;
    __syncthreads();
    for (int off = 128; off > 0; off >>= 1) {
        if (tid < off) lds[tid] += lds[tid + off];
        __syncthreads();
    }
    if (tid == 0) blocksum[b] = lds[0];
}

// ---------------------------------------------------------------------------
// K3b: exclusive scan of the block sums (two independent domains)
// ---------------------------------------------------------------------------
__device__ __forceinline__ void small_excl_scan(int* lds, int tid, int n,
                                                const int* __restrict__ in,
                                                int* __restrict__ outp, int in_off) {
    int v = (tid < n) ? in[in_off + tid] : 0;
    lds[tid] = v;
    __syncthreads();
    for (int off = 1; off < 256; off <<= 1) {
        int u = (tid >= off) ? lds[tid - off] : 0;
        __syncthreads();
        lds[tid] += u;
        __syncthreads();
    }
    int excl = (tid == 0) ? 0 : lds[tid - 1];
    if (tid < n) outp[in_off + tid] = excl;
    __syncthreads();
}

__global__ void scanB_kernel(const int* __restrict__ blocksum,
                             int* __restrict__ blockoff) {
    __shared__ int lds[256];
    int tid = threadIdx.x;
    small_excl_scan(lds, tid, SCAN_BT, blocksum, blockoff, 0);
    small_excl_scan(lds, tid, SCAN_BE, blocksum, blockoff, SCAN_BT);
}

// ---------------------------------------------------------------------------
// K3c: block-local exclusive scan + block offset -> startT / startE
// ---------------------------------------------------------------------------
__global__ void scanC_kernel(const int* __restrict__ histT,
                             const int* __restrict__ histE,
                             const int* __restrict__ blockoff,
                             int* __restrict__ startT,
                             int* __restrict__ startE) {
    __shared__ int lds[256];
    int b = blockIdx.x;
    int tid = threadIdx.x;
    const int* hist;
    int* start;
    int n, base;
    if (b < SCAN_BT) { hist = histT; start = startT; n = N_EDGES; base = b * 256; }
    else             { hist = histE; start = startE; n = N_ATOMS; base = (b - SCAN_BT) * 256; }
    int i = base + tid;
    int v = (i < n) ? hist[i] : 0;
    lds[tid] = v;
    __syncthreads();
    for (int off = 1; off < 256; off <<= 1) {
        int u = (tid >= off) ? lds[tid - off] : 0;
        __syncthreads();
        lds[tid] += u;
        __syncthreads();
    }
    int excl = ((tid == 0) ? 0 : lds[tid - 1]) + blockoff[b];
    if (i < n) start[i] = excl;
}

// ---------------------------------------------------------------------------
// K4: per-triplet geometry + per-head value; non-atomic write to sorted slot
// ---------------------------------------------------------------------------
__global__ void trip_kernel(const float* __restrict__ r,
                            const float* __restrict__ dnr,
                            const float* __restrict__ a_p,
                            const float* __restrict__ b_p,
                            const float* __restrict__ c_p,
                            const float* __restrict__ d_p,
                            const int* __restrict__ lg_src,
                            const int* __restrict__ lg_dst,
                            const int* __restrict__ za_e,
                            const int* __restrict__ zb_e,
                            const float* __restrict__ W,
                            const int* __restrict__ startT,
                            const int* __restrict__ rankT,
                            float4* __restrict__ val_sorted) {
    int t = blockIdx.x * blockDim.x + threadIdx.x;
    if (t >= N_TRIP) return;

    int e1 = lg_src[t];
    int e2 = lg_dst[t];

    float ax = r[e1 * 3 + 0];
    float ay = r[e1 * 3 + 1];
    float az = r[e1 * 3 + 2];
    float bx = r[e2 * 3 + 0];
    float by = r[e2 * 3 + 1];
    float bz = r[e2 * 3 + 2];

    // r1 = -r[e1], r2 = r[e2]  -> dot = -(a.b)
    float dot = -(ax * bx + ay * by + az * bz);
    float n1  = sqrtf(ax * ax + ay * ay + az * az);
    float n2  = sqrtf(bx * bx + by * by + bz * bz);
    float cosv = dot / (n1 * n2);
    cosv = fminf(fmaxf(cosv, -1.0f), 1.0f);
    cosv = fminf(fmaxf(cosv, -EPSV), EPSV);
    float theta = acosf(cosv);

    float dn  = dnr[t];
    float dn2 = dn * dn;

    const float* wp = W + (za_e[e1] * NTYPES + zb_e[e2]) * NH;

    float v[NH];
    #pragma unroll
    for (int h = 0; h < NH; ++h) {
        float A = a_p[h];
        float B = fmodf(b_p[h], PI_F);
        float C = c_p[h];
        float D = d_p[h];
        float ang = powf((cosf(A * theta + B) + 1.0f) * 0.5f, C);
        float rad = expf(-D * dn2);
        v[h] = wp[h] * ang * rad;
    }

    val_sorted[startT[e1] + rankT[t]] = make_float4(v[0], v[1], v[2], v[3]);
}

// ---------------------------------------------------------------------------
// K5: per-edge segmented mean over its triplets + edge->atom slot scatter
// ---------------------------------------------------------------------------
__global__ void edge_kernel(const int* __restrict__ src_idx,
                            const int* __restrict__ histT,
                            const int* __restrict__ startT,
                            const int* __restrict__ startE,
                            const int* __restrict__ rankE,
                            const float4* __restrict__ val_sorted,
                            int* __restrict__ edge_ord,
                            float4* __restrict__ edge_val) {
    int e = blockIdx.x * blockDim.x + threadIdx.x;
    if (e >= N_EDGES) return;

    int cnt = histT[e];
    int st  = startT[e];
    float sx = 0.f, sy = 0.f, sz = 0.f, sw = 0.f;
    for (int p = st; p < st + cnt; ++p) {
        float4 v = val_sorted[p];
        sx += v.x; sy += v.y; sz += v.z; sw += v.w;
    }
    float inv = 1.0f / (float)(cnt > 1 ? cnt : 1);
    edge_val[e] = make_float4(sx * inv, sy * inv, sz * inv, sw * inv);

    edge_ord[startE[src_idx[e]] + rankE[e]] = e;
}

// ---------------------------------------------------------------------------
// K6: per (atom, out): gather CSR edges, dot with value_emb, mean, store
// ---------------------------------------------------------------------------
__global__ void atom_kernel(const float* __restrict__ value_emb,
                            const int* __restrict__ zb_e,
                            const int* __restrict__ histE,
                            const int* __restrict__ startE,
                            const int* __restrict__ edge_ord,
                            const float4* __restrict__ edge_val,
                            float* __restrict__ out) {
    int id = blockIdx.x * blockDim.x + threadIdx.x;
    if (id >= N_ATOMS * NOUT) return;
    int n = id >> 6;
    int o = id & 63;

    int cnt = histE[n];
    int st  = startE[n];
    float acc = 0.f;
    for (int q = st; q < st + cnt; ++q) {
        int e = edge_ord[q];
        float4 m = edge_val[e];
        int zb = zb_e[e];
        float4 v = *reinterpret_cast<const float4*>(value_emb + zb * (NOUT * NH) + o * NH);
        acc += v.x * m.x + v.y * m.y + v.z * m.z + v.w * m.w;
    }
    out[id] = acc / (float)(cnt > 1 ? cnt : 1);
}

extern "C" void kernel_launch(void* const* d_in, const int* in_sizes, int n_in,
                              void* d_out, int out_size, void* d_ws, size_t ws_size,
                              hipStream_t stream) {
    const float* r         = (const float*)d_in[0];
    const float* dnr       = (const float*)d_in[1];
    const float* key_emb   = (const float*)d_in[2];
    const float* value_emb = (const float*)d_in[3];
    const float* a_p       = (const float*)d_in[4];
    const float* b_p       = (const float*)d_in[5];
    const float* c_p       = (const float*)d_in[6];
    const float* d_p       = (const float*)d_in[7];
    const int* src_idx   = (const int*)d_in[8];
    const int* dst_idx   = (const int*)d_in[9];
    const int* lg_src    = (const int*)d_in[10];
    const int* lg_dst    = (const int*)d_in[11];
    const int* atomic_number = (const int*)d_in[12];
    float* out = (float*)d_out;

    char* ws = (char*)d_ws;
    size_t off = 0;
    auto take = [&](size_t bytes) -> char* {
        char* p = ws + off;
        off = (off + bytes + 255) & ~(size_t)255;
        return p;
    };
    int*    histT      = (int*)   take(N_EDGES * sizeof(int));
    int*    histE      = (int*)   take(N_ATOMS * sizeof(int));
    int*    rankT      = (int*)   take((size_t)N_TRIP * sizeof(int));
    int*    rankE      = (int*)   take(N_EDGES * sizeof(int));
    int*    startT     = (int*)   take(N_EDGES * sizeof(int));
    int*    startE     = (int*)   take(N_ATOMS * sizeof(int));
    int*    blocksum   = (int*)   take(SCAN_NB * sizeof(int));
    int*    blockoff   = (int*)   take(SCAN_NB * sizeof(int));
    int*    za_e       = (int*)   take(N_EDGES * sizeof(int));
    int*    zb_e       = (int*)   take(N_EDGES * sizeof(int));
    float*  W          = (float*) take(NPAIRS * NH * sizeof(float));
    int*    edge_ord   = (int*)   take(N_EDGES * sizeof(int));
    float4* edge_val   = (float4*)take(N_EDGES * sizeof(float4));
    float4* val_sorted = (float4*)take((size_t)N_TRIP * sizeof(float4));

    {   // K1 prep: covers N_EDGES, NPAIRS, and both histogram zero-ranges
        int n = (N_EDGES > NPAIRS ? N_EDGES : NPAIRS);
        prep_kernel<<<(n + 255) / 256, 256, 0, stream>>>(
            key_emb, src_idx, dst_idx, atomic_number, W, za_e, zb_e, histT, histE);
    }
    hist_kernel<<<(N_TRIP + 255) / 256, 256, 0, stream>>>(
        lg_src, src_idx, histT, histE, rankT, rankE);
    scanA_kernel<<<SCAN_NB, 256, 0, stream>>>(histT, histE, blocksum);
    scanB_kernel<<<1, 256, 0, stream>>>(blocksum, blockoff);
    scanC_kernel<<<SCAN_NB, 256, 0, stream>>>(histT, histE, blockoff, startT, startE);
    trip_kernel<<<(N_TRIP + 255) / 256, 256, 0, stream>>>(
        r, dnr, a_p, b_p, c_p, d_p, lg_src, lg_dst, za_e, zb_e, W,
        startT, rankT, val_sorted);
    edge_kernel<<<(N_EDGES + 255) / 256, 256, 0, stream>>>(
        src_idx, histT, startT, startE, rankE, val_sorted, edge_ord, edge_val);
    atom_kernel<<<(N_ATOMS * NOUT + 255) / 256, 256, 0, stream>>>(
        value_emb, zb_e, histE, startE, edge_ord, edge_val, out);
}